// Round 3
// baseline (2711.242 us; speedup 1.0000x reference)
//
#include <hip/hip_runtime.h>

#define N_NODES 100000
#define IN_DIM 256
#define OUT_DIM 128
#define N_EDGES 3200000

#define NB 1563            // ceil(100000 / 64) buckets of 64 dst nodes
#define CAP 2560           // bucket capacity; mean 2048, std ~45 -> 11 sigma slack
#define PTILE 4000         // edges per partition block
#define PBLK 800           // 800 * 4000 = 3.2M exactly

// round-nearest-even f32 -> bf16 bits
__device__ __forceinline__ unsigned short f2bf(float f) {
    union { float f; unsigned int u; } v; v.f = f;
    unsigned int r = v.u + 0x7FFF + ((v.u >> 16) & 1);
    return (unsigned short)(r >> 16);
}

// ---------------------------------------------------------------------------
// Kernel 1: h(bf16) = X @ W   (f32 vector compute, bf16 store)
// 32 rows/block staged in LDS; each lane: 4 rows x 4 cols.
// ---------------------------------------------------------------------------
__global__ __launch_bounds__(256, 4) void gemm_kernel(const float* __restrict__ X,
                                                      const float* __restrict__ W,
                                                      unsigned short* __restrict__ hb) {
    __shared__ float As[32 * IN_DIM];                  // 32 KB
    const int tid = threadIdx.x;
    const int row0 = blockIdx.x * 32;

    const float4* Xv = (const float4*)(X + (long)row0 * IN_DIM);
    float4* Asv = (float4*)As;
#pragma unroll
    for (int i = 0; i < 8; ++i)
        Asv[tid + i * 256] = Xv[tid + i * 256];
    __syncthreads();

    const int wave = tid >> 6;
    const int lane = tid & 63;
    const int half = lane >> 5;
    const int c = (lane & 31) * 4;
    const int rloc = wave * 8 + half * 4;

    float acc[4][4] = {};
    const float* Asr = As + rloc * IN_DIM;

#pragma unroll 4
    for (int k = 0; k < IN_DIM; ++k) {
        const float4 w4 = *(const float4*)(W + k * OUT_DIM + c);
#pragma unroll
        for (int j = 0; j < 4; ++j) {
            const float a = Asr[j * IN_DIM + k];
            acc[j][0] += a * w4.x;
            acc[j][1] += a * w4.y;
            acc[j][2] += a * w4.z;
            acc[j][3] += a * w4.w;
        }
    }

#pragma unroll
    for (int j = 0; j < 4; ++j) {
        ushort4 o;
        o.x = f2bf(acc[j][0]); o.y = f2bf(acc[j][1]);
        o.z = f2bf(acc[j][2]); o.w = f2bf(acc[j][3]);
        *(ushort4*)(hb + (long)(row0 + rloc + j) * OUT_DIM + c) = o;
    }
}

// ---------------------------------------------------------------------------
// Kernel 2: zero bucket cursors
// ---------------------------------------------------------------------------
__global__ __launch_bounds__(256) void zero_cursor_kernel(int* __restrict__ cursor) {
    const int i = blockIdx.x * 256 + threadIdx.x;
    if (i < NB) cursor[i] = 0;
}

// ---------------------------------------------------------------------------
// Kernel 3: partition edges into 64-node dst-buckets.
// Per block: LDS histogram+rank over its 4000 edges, ONE global atomic per
// (block,bucket) to reserve space, then line-grouped pair writes.
// pair.x = src | (dst&63)<<20 ; pair.y = bits(val)
// ---------------------------------------------------------------------------
__global__ __launch_bounds__(256) void partition_kernel(const int* __restrict__ src,
                                                        const int* __restrict__ dst,
                                                        const float* __restrict__ vals,
                                                        int* __restrict__ cursor,
                                                        int2* __restrict__ pairs) {
    __shared__ int lhist[NB];
    __shared__ int lbase[NB];
    const int tid = threadIdx.x;
    const int base = blockIdx.x * PTILE;
    const int lim = base + PTILE;

    for (int i = tid; i < NB; i += 256) lhist[i] = 0;
    __syncthreads();

    int packed[16];                                    // (b<<13) | rank
#pragma unroll
    for (int k = 0; k < 16; ++k) {
        const int e = base + tid + k * 256;
        packed[k] = -1;
        if (e < lim) {
            const int b = dst[e] >> 6;
            const int r = atomicAdd(&lhist[b], 1);     // LDS atomic
            packed[k] = (b << 13) | r;
        }
    }
    __syncthreads();

    for (int bb = tid; bb < NB; bb += 256) {
        const int cnt = lhist[bb];
        if (cnt) lbase[bb] = atomicAdd(&cursor[bb], cnt);
    }
    __syncthreads();

#pragma unroll
    for (int k = 0; k < 16; ++k) {
        const int e = base + tid + k * 256;
        if (packed[k] >= 0) {
            const int b = packed[k] >> 13;
            const int r = packed[k] & 0x1FFF;
            const int pos = lbase[b] + r;
            if (pos < CAP) {                            // overflow safety
                const int d6 = dst[e] & 63;
                pairs[(long)b * CAP + pos] =
                    make_int2(src[e] | (d6 << 20), __float_as_int(vals[e]));
            }
        }
    }
}

// ---------------------------------------------------------------------------
// Kernel 4: bucket gather-reduce. One block per bucket; 64x128 f32 accumulator
// in 32 KB LDS (5 blocks/CU). Lane covers cols {l, l+64} -> 2-way LDS bank
// aliasing (free). Each out row written exactly once, bias folded in.
// ---------------------------------------------------------------------------
__global__ __launch_bounds__(256) void gather_kernel(const int* __restrict__ cursor,
                                                     const int2* __restrict__ pairs,
                                                     const unsigned short* __restrict__ hb,
                                                     const float* __restrict__ bias,
                                                     float* __restrict__ out) {
    __shared__ float acc[64 * OUT_DIM];                // 32 KB
    const int blk = blockIdx.x;
    const int tid = threadIdx.x;
    const int wid = tid >> 6;
    const int lane = tid & 63;

    float4* av = (float4*)acc;
    for (int i = tid; i < 64 * OUT_DIM / 4; i += 256)
        av[i] = make_float4(0.f, 0.f, 0.f, 0.f);
    __syncthreads();

    const int beg = (long)blk * CAP;
    const int cnt = min(cursor[blk], CAP);
    // per-wave contiguous chunk, 2-edge unrolled for load ILP
    const int wbeg = beg + (cnt * wid) / 4;
    const int wend = beg + (cnt * (wid + 1)) / 4;

    int j = wbeg;
    for (; j + 1 < wend; j += 2) {
        const int2 p0 = pairs[j];
        const int2 p1 = pairs[j + 1];
        const int s0 = p0.x & 0xFFFFF, r0 = (p0.x >> 20) & 63;
        const int s1 = p1.x & 0xFFFFF, r1 = (p1.x >> 20) & 63;
        const unsigned short ua0 = hb[(long)s0 * OUT_DIM + lane];
        const unsigned short ub0 = hb[(long)s0 * OUT_DIM + 64 + lane];
        const unsigned short ua1 = hb[(long)s1 * OUT_DIM + lane];
        const unsigned short ub1 = hb[(long)s1 * OUT_DIM + 64 + lane];
        const float v0 = __int_as_float(p0.y);
        const float v1 = __int_as_float(p1.y);
        atomicAdd(&acc[r0 * OUT_DIM + lane],      v0 * __uint_as_float((unsigned)ua0 << 16));
        atomicAdd(&acc[r0 * OUT_DIM + 64 + lane], v0 * __uint_as_float((unsigned)ub0 << 16));
        atomicAdd(&acc[r1 * OUT_DIM + lane],      v1 * __uint_as_float((unsigned)ua1 << 16));
        atomicAdd(&acc[r1 * OUT_DIM + 64 + lane], v1 * __uint_as_float((unsigned)ub1 << 16));
    }
    if (j < wend) {
        const int2 p0 = pairs[j];
        const int s0 = p0.x & 0xFFFFF, r0 = (p0.x >> 20) & 63;
        const unsigned short ua0 = hb[(long)s0 * OUT_DIM + lane];
        const unsigned short ub0 = hb[(long)s0 * OUT_DIM + 64 + lane];
        const float v0 = __int_as_float(p0.y);
        atomicAdd(&acc[r0 * OUT_DIM + lane],      v0 * __uint_as_float((unsigned)ua0 << 16));
        atomicAdd(&acc[r0 * OUT_DIM + 64 + lane], v0 * __uint_as_float((unsigned)ub0 << 16));
    }
    __syncthreads();

    // epilogue: out[node] = acc + bias, coalesced float4, one write per row
    const float4* b4 = (const float4*)bias;
    for (int i = tid; i < 64 * OUT_DIM / 4; i += 256) {
        const int row = i >> 5;                        // 32 float4 per row
        const int c4 = i & 31;
        const int node = blk * 64 + row;
        if (node < N_NODES) {
            float4 a = av[i];
            const float4 bb = b4[c4];
            a.x += bb.x; a.y += bb.y; a.z += bb.z; a.w += bb.w;
            *(float4*)(out + (long)node * OUT_DIM + c4 * 4) = a;
        }
    }
}

// ---------------------------------------------------------------------------
extern "C" void kernel_launch(void* const* d_in, const int* in_sizes, int n_in,
                              void* d_out, int out_size, void* d_ws, size_t ws_size,
                              hipStream_t stream) {
    const float* X     = (const float*)d_in[0];
    const int*   esrc  = (const int*)d_in[1];
    const int*   edst  = (const int*)d_in[2];
    const float* evals = (const float*)d_in[3];
    const float* W     = (const float*)d_in[4];
    const float* b     = (const float*)d_in[5];
    float* out = (float*)d_out;

    // workspace layout
    char* ws = (char*)d_ws;
    unsigned short* hb = (unsigned short*)(ws);              // 25,600,000 B
    int2* pairs        = (int2*)(ws + 25600000);             // NB*CAP*8 = 32,010,240 B
    int*  cursor       = (int*) (ws + 25600000 + 32010240);  // 6,252 B

    gemm_kernel<<<dim3(N_NODES / 32), dim3(256), 0, stream>>>(X, W, hb);
    zero_cursor_kernel<<<dim3((NB + 255) / 256), dim3(256), 0, stream>>>(cursor);
    partition_kernel<<<dim3(PBLK), dim3(256), 0, stream>>>(esrc, edst, evals, cursor, pairs);
    gather_kernel<<<dim3(NB), dim3(256), 0, stream>>>(cursor, pairs, hb, b, out);
}

// Round 4
// 928.800 us; speedup vs baseline: 2.9191x; 2.9191x over previous
//
#include <hip/hip_runtime.h>

#define N_NODES 100000
#define IN_DIM 256
#define OUT_DIM 128
#define N_EDGES 3200000

#define NB 1563            // ceil(100000 / 64) buckets of 64 dst nodes
#define CAP 2560           // bucket capacity; mean 2048, sigma ~45 -> 11 sigma slack
#define PTILE 4000         // edges per partition block
#define PBLK 800           // 800 * 4000 = 3.2M exactly

// round-nearest-even f32 -> bf16 bits
__device__ __forceinline__ unsigned short f2bf(float f) {
    union { float f; unsigned int u; } v; v.f = f;
    unsigned int r = v.u + 0x7FFF + ((v.u >> 16) & 1);
    return (unsigned short)(r >> 16);
}

// ---------------------------------------------------------------------------
// Kernel 1: h(bf16) = X @ W   (f32 vector compute, bf16 store) — unchanged R3
// ---------------------------------------------------------------------------
__global__ __launch_bounds__(256, 4) void gemm_kernel(const float* __restrict__ X,
                                                      const float* __restrict__ W,
                                                      unsigned short* __restrict__ hb) {
    __shared__ float As[32 * IN_DIM];                  // 32 KB
    const int tid = threadIdx.x;
    const int row0 = blockIdx.x * 32;

    const float4* Xv = (const float4*)(X + (long)row0 * IN_DIM);
    float4* Asv = (float4*)As;
#pragma unroll
    for (int i = 0; i < 8; ++i)
        Asv[tid + i * 256] = Xv[tid + i * 256];
    __syncthreads();

    const int wave = tid >> 6;
    const int lane = tid & 63;
    const int half = lane >> 5;
    const int c = (lane & 31) * 4;
    const int rloc = wave * 8 + half * 4;

    float acc[4][4] = {};
    const float* Asr = As + rloc * IN_DIM;

#pragma unroll 4
    for (int k = 0; k < IN_DIM; ++k) {
        const float4 w4 = *(const float4*)(W + k * OUT_DIM + c);
#pragma unroll
        for (int j = 0; j < 4; ++j) {
            const float a = Asr[j * IN_DIM + k];
            acc[j][0] += a * w4.x;
            acc[j][1] += a * w4.y;
            acc[j][2] += a * w4.z;
            acc[j][3] += a * w4.w;
        }
    }

#pragma unroll
    for (int j = 0; j < 4; ++j) {
        ushort4 o;
        o.x = f2bf(acc[j][0]); o.y = f2bf(acc[j][1]);
        o.z = f2bf(acc[j][2]); o.w = f2bf(acc[j][3]);
        *(ushort4*)(hb + (long)(row0 + rloc + j) * OUT_DIM + c) = o;
    }
}

// ---------------------------------------------------------------------------
// Kernel 2: zero bucket cursors
// ---------------------------------------------------------------------------
__global__ __launch_bounds__(256) void zero_cursor_kernel(int* __restrict__ cursor) {
    const int i = blockIdx.x * 256 + threadIdx.x;
    if (i < NB) cursor[i] = 0;
}

// ---------------------------------------------------------------------------
// Kernel 3: partition edges into 64-node dst-buckets — unchanged R3.
// pair.x = src | (dst&63)<<20 ; pair.y = bits(val)
// ---------------------------------------------------------------------------
__global__ __launch_bounds__(256) void partition_kernel(const int* __restrict__ src,
                                                        const int* __restrict__ dst,
                                                        const float* __restrict__ vals,
                                                        int* __restrict__ cursor,
                                                        int2* __restrict__ pairs) {
    __shared__ int lhist[NB];
    __shared__ int lbase[NB];
    const int tid = threadIdx.x;
    const int base = blockIdx.x * PTILE;
    const int lim = base + PTILE;

    for (int i = tid; i < NB; i += 256) lhist[i] = 0;
    __syncthreads();

    int packed[16];                                    // (b<<13) | rank
#pragma unroll
    for (int k = 0; k < 16; ++k) {
        const int e = base + tid + k * 256;
        packed[k] = -1;
        if (e < lim) {
            const int b = dst[e] >> 6;
            const int r = atomicAdd(&lhist[b], 1);     // LDS int atomic (native)
            packed[k] = (b << 13) | r;
        }
    }
    __syncthreads();

    for (int bb = tid; bb < NB; bb += 256) {
        const int cnt = lhist[bb];
        if (cnt) lbase[bb] = atomicAdd(&cursor[bb], cnt);
    }
    __syncthreads();

#pragma unroll
    for (int k = 0; k < 16; ++k) {
        const int e = base + tid + k * 256;
        if (packed[k] >= 0) {
            const int b = packed[k] >> 13;
            const int r = packed[k] & 0x1FFF;
            const int pos = lbase[b] + r;
            if (pos < CAP) {                            // overflow safety (11 sigma)
                const int d6 = dst[e] & 63;
                pairs[(long)b * CAP + pos] =
                    make_int2(src[e] | (d6 << 20), __float_as_int(vals[e]));
            }
        }
    }
}

// ---------------------------------------------------------------------------
// Kernel 4: bucket gather-reduce, NO atomics, NO barriers.
// One block per bucket. Each wave exclusively owns 16 of the 64 rows in a
// private 8 KB LDS region. Every wave scans all pairs (wave-uniform 8 B
// broadcast loads, L1-hot across the 4 waves) and processes only its rows:
// 1 coalesced uint load (2 bf16 cols) + 2 fma + float2 LDS RMW per edge.
// DS ops from a wave are in-order -> same-row RMW across iterations is safe.
// ---------------------------------------------------------------------------
__global__ __launch_bounds__(256) void gather_kernel(const int* __restrict__ cursor,
                                                     const int2* __restrict__ pairs,
                                                     const unsigned short* __restrict__ hb,
                                                     const float* __restrict__ bias,
                                                     float* __restrict__ out) {
    __shared__ float acc[4][16 * OUT_DIM];             // 4 x 8 KB = 32 KB
    const int blk = blockIdx.x;
    const int tid = threadIdx.x;
    const int wid = tid >> 6;
    const int lane = tid & 63;
    const int c = lane * 2;                            // cols {c, c+1}

    float* my = acc[wid];
    // zero own region: 2048 floats / wave = 8 float4 / lane
    float4* mv = (float4*)my;
#pragma unroll
    for (int i = 0; i < 8; ++i)
        mv[lane + i * 64] = make_float4(0.f, 0.f, 0.f, 0.f);

    const long beg = (long)blk * CAP;
    const int cnt = min(cursor[blk], CAP);

#pragma unroll 4
    for (int j = 0; j < cnt; ++j) {
        const int2 p = pairs[beg + j];                 // wave-uniform broadcast
        const int r = (p.x >> 20) & 63;
        if ((r >> 4) == wid) {                         // wave-uniform branch
            const int s = p.x & 0xFFFFF;
            const unsigned u = *(const unsigned*)(hb + (long)s * OUT_DIM + c);
            const float v = __int_as_float(p.y);
            const float h0 = __uint_as_float(u << 16);          // col c
            const float h1 = __uint_as_float(u & 0xFFFF0000u);  // col c+1
            float2 a = *(float2*)&my[(r & 15) * OUT_DIM + c];
            a.x += v * h0;
            a.y += v * h1;
            *(float2*)&my[(r & 15) * OUT_DIM + c] = a;
        }
    }

    // epilogue: out[node] = acc + bias; each wave writes its own 16 rows.
    const float2 bb = *(const float2*)(bias + c);
#pragma unroll
    for (int rr = 0; rr < 16; ++rr) {
        const int node = blk * 64 + wid * 16 + rr;
        if (node < N_NODES) {
            float2 a = *(float2*)&my[rr * OUT_DIM + c];
            a.x += bb.x; a.y += bb.y;
            *(float2*)(out + (long)node * OUT_DIM + c) = a;
        }
    }
}

// ---------------------------------------------------------------------------
extern "C" void kernel_launch(void* const* d_in, const int* in_sizes, int n_in,
                              void* d_out, int out_size, void* d_ws, size_t ws_size,
                              hipStream_t stream) {
    const float* X     = (const float*)d_in[0];
    const int*   esrc  = (const int*)d_in[1];
    const int*   edst  = (const int*)d_in[2];
    const float* evals = (const float*)d_in[3];
    const float* W     = (const float*)d_in[4];
    const float* b     = (const float*)d_in[5];
    float* out = (float*)d_out;

    // workspace layout
    char* ws = (char*)d_ws;
    unsigned short* hb = (unsigned short*)(ws);              // 25,600,000 B
    int2* pairs        = (int2*)(ws + 25600000);             // NB*CAP*8 = 32,010,240 B
    int*  cursor       = (int*) (ws + 25600000 + 32010240);  // 6,252 B

    gemm_kernel<<<dim3(N_NODES / 32), dim3(256), 0, stream>>>(X, W, hb);
    zero_cursor_kernel<<<dim3((NB + 255) / 256), dim3(256), 0, stream>>>(cursor);
    partition_kernel<<<dim3(PBLK), dim3(256), 0, stream>>>(esrc, edst, evals, cursor, pairs);
    gather_kernel<<<dim3(NB), dim3(256), 0, stream>>>(cursor, pairs, hb, b, out);
}

// Round 5
// 501.808 us; speedup vs baseline: 5.4029x; 1.8509x over previous
//
#include <hip/hip_runtime.h>

#define N_NODES 100000
#define IN_DIM 256
#define OUT_DIM 128
#define N_EDGES 3200000

#define NB 1563            // ceil(100000 / 64) buckets of 64 dst nodes
#define CAP 2560           // bucket capacity; mean 2048, sigma ~45 -> 11 sigma slack
#define PTILE 4000         // edges per partition block
#define PBLK 800           // 800 * 4000 = 3.2M exactly

// round-nearest-even f32 -> bf16 bits
__device__ __forceinline__ unsigned short f2bf(float f) {
    union { float f; unsigned int u; } v; v.f = f;
    unsigned int r = v.u + 0x7FFF + ((v.u >> 16) & 1);
    return (unsigned short)(r >> 16);
}

// ---------------------------------------------------------------------------
// Kernel 1: h(bf16) = X @ W   (f32 vector compute, bf16 store) — unchanged
// ---------------------------------------------------------------------------
__global__ __launch_bounds__(256, 4) void gemm_kernel(const float* __restrict__ X,
                                                      const float* __restrict__ W,
                                                      unsigned short* __restrict__ hb) {
    __shared__ float As[32 * IN_DIM];                  // 32 KB
    const int tid = threadIdx.x;
    const int row0 = blockIdx.x * 32;

    const float4* Xv = (const float4*)(X + (long)row0 * IN_DIM);
    float4* Asv = (float4*)As;
#pragma unroll
    for (int i = 0; i < 8; ++i)
        Asv[tid + i * 256] = Xv[tid + i * 256];
    __syncthreads();

    const int wave = tid >> 6;
    const int lane = tid & 63;
    const int half = lane >> 5;
    const int c = (lane & 31) * 4;
    const int rloc = wave * 8 + half * 4;

    float acc[4][4] = {};
    const float* Asr = As + rloc * IN_DIM;

#pragma unroll 4
    for (int k = 0; k < IN_DIM; ++k) {
        const float4 w4 = *(const float4*)(W + k * OUT_DIM + c);
#pragma unroll
        for (int j = 0; j < 4; ++j) {
            const float a = Asr[j * IN_DIM + k];
            acc[j][0] += a * w4.x;
            acc[j][1] += a * w4.y;
            acc[j][2] += a * w4.z;
            acc[j][3] += a * w4.w;
        }
    }

#pragma unroll
    for (int j = 0; j < 4; ++j) {
        ushort4 o;
        o.x = f2bf(acc[j][0]); o.y = f2bf(acc[j][1]);
        o.z = f2bf(acc[j][2]); o.w = f2bf(acc[j][3]);
        *(ushort4*)(hb + (long)(row0 + rloc + j) * OUT_DIM + c) = o;
    }
}

// ---------------------------------------------------------------------------
// Kernel 2: zero bucket cursors
// ---------------------------------------------------------------------------
__global__ __launch_bounds__(256) void zero_cursor_kernel(int* __restrict__ cursor) {
    const int i = blockIdx.x * 256 + threadIdx.x;
    if (i < NB) cursor[i] = 0;
}

// ---------------------------------------------------------------------------
// Kernel 3: partition edges into 64-node dst-buckets — unchanged.
// pair.x = src | (dst&63)<<20 ; pair.y = bits(val)
// ---------------------------------------------------------------------------
__global__ __launch_bounds__(256) void partition_kernel(const int* __restrict__ src,
                                                        const int* __restrict__ dst,
                                                        const float* __restrict__ vals,
                                                        int* __restrict__ cursor,
                                                        int2* __restrict__ pairs) {
    __shared__ int lhist[NB];
    __shared__ int lbase[NB];
    const int tid = threadIdx.x;
    const int base = blockIdx.x * PTILE;
    const int lim = base + PTILE;

    for (int i = tid; i < NB; i += 256) lhist[i] = 0;
    __syncthreads();

    int packed[16];                                    // (b<<13) | rank
#pragma unroll
    for (int k = 0; k < 16; ++k) {
        const int e = base + tid + k * 256;
        packed[k] = -1;
        if (e < lim) {
            const int b = dst[e] >> 6;
            const int r = atomicAdd(&lhist[b], 1);     // LDS int atomic (native)
            packed[k] = (b << 13) | r;
        }
    }
    __syncthreads();

    for (int bb = tid; bb < NB; bb += 256) {
        const int cnt = lhist[bb];
        if (cnt) lbase[bb] = atomicAdd(&cursor[bb], cnt);
    }
    __syncthreads();

#pragma unroll
    for (int k = 0; k < 16; ++k) {
        const int e = base + tid + k * 256;
        if (packed[k] >= 0) {
            const int b = packed[k] >> 13;
            const int r = packed[k] & 0x1FFF;
            const int pos = lbase[b] + r;
            if (pos < CAP) {                            // overflow safety (11 sigma)
                const int d6 = dst[e] & 63;
                pairs[(long)b * CAP + pos] =
                    make_int2(src[e] | (d6 << 20), __float_as_int(vals[e]));
            }
        }
    }
}

// ---------------------------------------------------------------------------
// Kernel 4: bucket gather-reduce v3.
// Phase 1: counting-sort the bucket's pairs by exact dst row into LDS
//          (native LDS int atomics for ranks + wave-shfl scan of 64 counts).
// Phase 2: wave w owns rows [w*16, w*16+16); per row, edges are contiguous
//          in LDS -> float2 REGISTER accumulation (4-way ILP split), fully
//          pipelineable hb gathers (coalesced 256 B/wave), no LDS RMW chain.
// Each out row written exactly once with bias folded in.
// ---------------------------------------------------------------------------
__global__ __launch_bounds__(256) void gather_kernel(const int* __restrict__ cursor,
                                                     const int2* __restrict__ pairs,
                                                     const unsigned short* __restrict__ hb,
                                                     const float* __restrict__ bias,
                                                     float* __restrict__ out) {
    __shared__ int2 lp[CAP];                           // 20,480 B sorted pairs
    __shared__ int rcnt[64];
    __shared__ int rbase[64];
    const int blk = blockIdx.x;
    const int tid = threadIdx.x;
    const int wid = tid >> 6;
    const int lane = tid & 63;
    const int c = lane * 2;                            // cols {c, c+1}

    const long beg = (long)blk * CAP;
    const int cnt = min(cursor[blk], CAP);

    if (tid < 64) rcnt[tid] = 0;
    __syncthreads();

    // ---- phase 1a: rank (CAP = 10 * 256 exactly)
    int2 sp[10];
    int  sr[10];
#pragma unroll
    for (int k = 0; k < 10; ++k) {
        const int i = tid + k * 256;
        sr[k] = -1;
        if (i < cnt) {
            const int2 p = pairs[beg + i];             // coalesced
            const int r = (p.x >> 20) & 63;
            const int rk = atomicAdd(&rcnt[r], 1);     // native LDS int atomic
            sp[k] = p;
            sr[k] = (r << 13) | rk;                    // rank < 8192
        }
    }
    __syncthreads();

    // ---- phase 1b: exclusive scan of 64 row counts (wave 0, shfl scan)
    if (wid == 0) {
        const int v = rcnt[lane];
        int incl = v;
#pragma unroll
        for (int off = 1; off < 64; off <<= 1) {
            const int t = __shfl_up(incl, off);
            if (lane >= off) incl += t;
        }
        rbase[lane] = incl - v;
    }
    __syncthreads();

    // ---- phase 1c: scatter into sorted LDS array
#pragma unroll
    for (int k = 0; k < 10; ++k) {
        if (sr[k] >= 0)
            lp[rbase[sr[k] >> 13] + (sr[k] & 0x1FFF)] = sp[k];
    }
    __syncthreads();

    // ---- phase 2: per-row register accumulation
    const float2 bb = *(const float2*)(bias + c);
#pragma unroll 1
    for (int rr = 0; rr < 16; ++rr) {
        const int r = wid * 16 + rr;
        const int node = blk * 64 + r;
        if (node >= N_NODES) break;                    // only last block's tail
        const int rb = rbase[r];
        const int re = rb + rcnt[r];

        float2 a0 = make_float2(0.f, 0.f), a1 = make_float2(0.f, 0.f);
        float2 a2 = make_float2(0.f, 0.f), a3 = make_float2(0.f, 0.f);
        int j = rb;
        for (; j + 3 < re; j += 4) {                   // 4 independent gathers
            const int2 p0 = lp[j],     p1 = lp[j + 1];
            const int2 p2 = lp[j + 2], p3 = lp[j + 3];
            const unsigned u0 = *(const unsigned*)(hb + (long)(p0.x & 0xFFFFF) * OUT_DIM + c);
            const unsigned u1 = *(const unsigned*)(hb + (long)(p1.x & 0xFFFFF) * OUT_DIM + c);
            const unsigned u2 = *(const unsigned*)(hb + (long)(p2.x & 0xFFFFF) * OUT_DIM + c);
            const unsigned u3 = *(const unsigned*)(hb + (long)(p3.x & 0xFFFFF) * OUT_DIM + c);
            const float v0 = __int_as_float(p0.y), v1 = __int_as_float(p1.y);
            const float v2 = __int_as_float(p2.y), v3 = __int_as_float(p3.y);
            a0.x += v0 * __uint_as_float(u0 << 16);
            a0.y += v0 * __uint_as_float(u0 & 0xFFFF0000u);
            a1.x += v1 * __uint_as_float(u1 << 16);
            a1.y += v1 * __uint_as_float(u1 & 0xFFFF0000u);
            a2.x += v2 * __uint_as_float(u2 << 16);
            a2.y += v2 * __uint_as_float(u2 & 0xFFFF0000u);
            a3.x += v3 * __uint_as_float(u3 << 16);
            a3.y += v3 * __uint_as_float(u3 & 0xFFFF0000u);
        }
        for (; j < re; ++j) {
            const int2 p0 = lp[j];
            const unsigned u0 = *(const unsigned*)(hb + (long)(p0.x & 0xFFFFF) * OUT_DIM + c);
            const float v0 = __int_as_float(p0.y);
            a0.x += v0 * __uint_as_float(u0 << 16);
            a0.y += v0 * __uint_as_float(u0 & 0xFFFF0000u);
        }
        float2 o;
        o.x = bb.x + (a0.x + a1.x) + (a2.x + a3.x);
        o.y = bb.y + (a0.y + a1.y) + (a2.y + a3.y);
        *(float2*)(out + (long)node * OUT_DIM + c) = o;
    }
}

// ---------------------------------------------------------------------------
extern "C" void kernel_launch(void* const* d_in, const int* in_sizes, int n_in,
                              void* d_out, int out_size, void* d_ws, size_t ws_size,
                              hipStream_t stream) {
    const float* X     = (const float*)d_in[0];
    const int*   esrc  = (const int*)d_in[1];
    const int*   edst  = (const int*)d_in[2];
    const float* evals = (const float*)d_in[3];
    const float* W     = (const float*)d_in[4];
    const float* b     = (const float*)d_in[5];
    float* out = (float*)d_out;

    // workspace layout
    char* ws = (char*)d_ws;
    unsigned short* hb = (unsigned short*)(ws);              // 25,600,000 B
    int2* pairs        = (int2*)(ws + 25600000);             // NB*CAP*8 = 32,010,240 B
    int*  cursor       = (int*) (ws + 25600000 + 32010240);  // 6,252 B

    gemm_kernel<<<dim3(N_NODES / 32), dim3(256), 0, stream>>>(X, W, hb);
    zero_cursor_kernel<<<dim3((NB + 255) / 256), dim3(256), 0, stream>>>(cursor);
    partition_kernel<<<dim3(PBLK), dim3(256), 0, stream>>>(esrc, edst, evals, cursor, pairs);
    gather_kernel<<<dim3(NB), dim3(256), 0, stream>>>(cursor, pairs, hb, b, out);
}

// Round 6
// 398.727 us; speedup vs baseline: 6.7997x; 1.2585x over previous
//
#include <hip/hip_runtime.h>

#define N_NODES 100000
#define IN_DIM 256
#define OUT_DIM 128
#define N_EDGES 3200000

#define NB 1563            // ceil(100000 / 64) buckets of 64 dst nodes
#define CAP 2560           // bucket capacity; mean 2048, sigma ~45 -> 11 sigma slack
#define PTILE 12800        // edges per partition block (two-pass, no reg limit)
#define PBLK 250           // 250 * 12800 = 3.2M exactly

typedef __attribute__((ext_vector_type(8))) short short8;   // 8 bf16 (4 VGPRs)
typedef __attribute__((ext_vector_type(4))) float float4v;  // 4 f32 acc

// round-nearest-even f32 -> bf16 bits
__device__ __forceinline__ unsigned short f2bf(float f) {
    union { float f; unsigned int u; } v; v.f = f;
    unsigned int r = v.u + 0x7FFF + ((v.u >> 16) & 1);
    return (unsigned short)(r >> 16);
}

// ---------------------------------------------------------------------------
// Kernel 0: swizzle W (f32 256x128) into bf16 MFMA B-fragment-major order.
// Fragment f = (q*8 + ct)*64 + lane holds B[k = q*32 + (lane>>4)*8 + j]
//                                        [n = ct*16 + (lane&15)], j=0..7,
// stored as 16 contiguous bytes -> GEMM loads each B frag as one dwordx4.
// 4096 fragments total (64 KB). One-time, L2-hot.
// ---------------------------------------------------------------------------
__global__ __launch_bounds__(256) void wconv_kernel(const float* __restrict__ W,
                                                    unsigned short* __restrict__ Wf) {
    const int f = blockIdx.x * 256 + threadIdx.x;      // < 4096
    const int lane = f & 63;
    const int qc = f >> 6;
    const int q = qc >> 3, ct = qc & 7;
    const int n = ct * 16 + (lane & 15);
    const int k0 = q * 32 + (lane >> 4) * 8;
    unsigned int o[4];
#pragma unroll
    for (int jj = 0; jj < 4; ++jj) {
        const unsigned short lo = f2bf(W[(k0 + 2 * jj) * OUT_DIM + n]);
        const unsigned short hi = f2bf(W[(k0 + 2 * jj + 1) * OUT_DIM + n]);
        o[jj] = (unsigned)lo | ((unsigned)hi << 16);
    }
    ((uint4*)Wf)[f] = make_uint4(o[0], o[1], o[2], o[3]);
}

// ---------------------------------------------------------------------------
// Kernel 1: hb(bf16) = X @ W via mfma_f32_16x16x32_bf16. No LDS.
// Block = 4 waves x 16 rows = 64 rows. Wave holds its A fragments
// (A[m=lane&15][k=quad*8+j], verified layout) in 32 VGPRs, loaded once from
// X with inline cvt. B frags: one coalesced 16 B load each from Wf (L1-hot).
// C/D: col=lane&15, row=quad*4+reg (m89-verified).
// ---------------------------------------------------------------------------
__global__ __launch_bounds__(256) void gemm_kernel(const float* __restrict__ X,
                                                   const unsigned short* __restrict__ Wf,
                                                   unsigned short* __restrict__ hb) {
    const int tid = threadIdx.x;
    const int wid = tid >> 6;
    const int lane = tid & 63;
    const int m = lane & 15;
    const int quad = lane >> 4;
    const int row0 = blockIdx.x * 64 + wid * 16;       // wave's 16-row tile

    // ---- load all 8 A fragments (K = 8 x 32)
    const int rl = min(row0 + m, N_NODES - 1);         // clamp tail reads
    const float* xr = X + (long)rl * IN_DIM + quad * 8;
    short8 afrag[8];
#pragma unroll
    for (int q = 0; q < 8; ++q) {
        const float4 xa = *(const float4*)(xr + q * 32);
        const float4 xb = *(const float4*)(xr + q * 32 + 4);
        short8 f;
        f[0] = (short)f2bf(xa.x); f[1] = (short)f2bf(xa.y);
        f[2] = (short)f2bf(xa.z); f[3] = (short)f2bf(xa.w);
        f[4] = (short)f2bf(xb.x); f[5] = (short)f2bf(xb.y);
        f[6] = (short)f2bf(xb.z); f[7] = (short)f2bf(xb.w);
        afrag[q] = f;
    }

    const short8* wfrag = (const short8*)Wf;
#pragma unroll 1
    for (int ct = 0; ct < 8; ++ct) {
        float4v acc = {0.f, 0.f, 0.f, 0.f};
#pragma unroll
        for (int q = 0; q < 8; ++q) {
            const short8 bfr = wfrag[(q * 8 + ct) * 64 + lane];
            acc = __builtin_amdgcn_mfma_f32_16x16x32_bf16(afrag[q], bfr, acc, 0, 0, 0);
        }
        const int col = ct * 16 + m;
#pragma unroll
        for (int r = 0; r < 4; ++r) {
            const int row = row0 + quad * 4 + r;
            if (row < N_NODES)
                hb[(long)row * OUT_DIM + col] = f2bf(acc[r]);
        }
    }
}

// ---------------------------------------------------------------------------
// Kernel 2: zero bucket cursors
// ---------------------------------------------------------------------------
__global__ __launch_bounds__(256) void zero_cursor_kernel(int* __restrict__ cursor) {
    const int i = blockIdx.x * 256 + threadIdx.x;
    if (i < NB) cursor[i] = 0;
}

// ---------------------------------------------------------------------------
// Kernel 3: partition edges into 64-node dst-buckets — two-pass.
// Pass A: LDS histogram (counts only). Reserve global bases (1 atomic per
// nonzero (block,bucket)). Pass B: re-read edges, re-rank with a second LDS
// histogram (ranks are a fresh permutation — only counts must match), write.
// PTILE=12800 -> avg 8.2 consecutive pairs per (block,bucket) run.
// pair.x = src | (dst&63)<<20 ; pair.y = bits(val)
// ---------------------------------------------------------------------------
__global__ __launch_bounds__(512) void partition_kernel(const int* __restrict__ src,
                                                        const int* __restrict__ dst,
                                                        const float* __restrict__ vals,
                                                        int* __restrict__ cursor,
                                                        int2* __restrict__ pairs) {
    __shared__ int lhist[NB];
    __shared__ int lbase[NB];
    const int tid = threadIdx.x;
    const int base = blockIdx.x * PTILE;

    for (int i = tid; i < NB; i += 512) lhist[i] = 0;
    __syncthreads();

#pragma unroll 5
    for (int k = 0; k < PTILE / 512; ++k)
        atomicAdd(&lhist[dst[base + tid + k * 512] >> 6], 1);
    __syncthreads();

    for (int i = tid; i < NB; i += 512) {
        const int c = lhist[i];
        if (c) lbase[i] = atomicAdd(&cursor[i], c);
    }
    __syncthreads();
    for (int i = tid; i < NB; i += 512) lhist[i] = 0;
    __syncthreads();

#pragma unroll 5
    for (int k = 0; k < PTILE / 512; ++k) {
        const int e = base + tid + k * 512;            // dst re-read is L1/L2-hot
        const int d = dst[e];
        const int b = d >> 6;
        const int r = atomicAdd(&lhist[b], 1);
        const int pos = lbase[b] + r;
        if (pos < CAP)                                  // 11-sigma overflow guard
            pairs[(long)b * CAP + pos] =
                make_int2(src[e] | ((d & 63) << 20), __float_as_int(vals[e]));
    }
}

// ---------------------------------------------------------------------------
// Kernel 4: bucket gather-reduce (counting-sort to LDS + register acc) —
// unchanged from R5.
// ---------------------------------------------------------------------------
__global__ __launch_bounds__(256) void gather_kernel(const int* __restrict__ cursor,
                                                     const int2* __restrict__ pairs,
                                                     const unsigned short* __restrict__ hb,
                                                     const float* __restrict__ bias,
                                                     float* __restrict__ out) {
    __shared__ int2 lp[CAP];                           // 20,480 B sorted pairs
    __shared__ int rcnt[64];
    __shared__ int rbase[64];
    const int blk = blockIdx.x;
    const int tid = threadIdx.x;
    const int wid = tid >> 6;
    const int lane = tid & 63;
    const int c = lane * 2;                            // cols {c, c+1}

    const long beg = (long)blk * CAP;
    const int cnt = min(cursor[blk], CAP);

    if (tid < 64) rcnt[tid] = 0;
    __syncthreads();

    int2 sp[10];
    int  sr[10];
#pragma unroll
    for (int k = 0; k < 10; ++k) {
        const int i = tid + k * 256;
        sr[k] = -1;
        if (i < cnt) {
            const int2 p = pairs[beg + i];
            const int r = (p.x >> 20) & 63;
            const int rk = atomicAdd(&rcnt[r], 1);     // native LDS int atomic
            sp[k] = p;
            sr[k] = (r << 13) | rk;
        }
    }
    __syncthreads();

    if (wid == 0) {
        const int v = rcnt[lane];
        int incl = v;
#pragma unroll
        for (int off = 1; off < 64; off <<= 1) {
            const int t = __shfl_up(incl, off);
            if (lane >= off) incl += t;
        }
        rbase[lane] = incl - v;
    }
    __syncthreads();

#pragma unroll
    for (int k = 0; k < 10; ++k) {
        if (sr[k] >= 0)
            lp[rbase[sr[k] >> 13] + (sr[k] & 0x1FFF)] = sp[k];
    }
    __syncthreads();

    const float2 bb = *(const float2*)(bias + c);
#pragma unroll 1
    for (int rr = 0; rr < 16; ++rr) {
        const int r = wid * 16 + rr;
        const int node = blk * 64 + r;
        if (node >= N_NODES) break;
        const int rb = rbase[r];
        const int re = rb + rcnt[r];

        float2 a0 = make_float2(0.f, 0.f), a1 = make_float2(0.f, 0.f);
        float2 a2 = make_float2(0.f, 0.f), a3 = make_float2(0.f, 0.f);
        int j = rb;
        for (; j + 3 < re; j += 4) {
            const int2 p0 = lp[j],     p1 = lp[j + 1];
            const int2 p2 = lp[j + 2], p3 = lp[j + 3];
            const unsigned u0 = *(const unsigned*)(hb + (long)(p0.x & 0xFFFFF) * OUT_DIM + c);
            const unsigned u1 = *(const unsigned*)(hb + (long)(p1.x & 0xFFFFF) * OUT_DIM + c);
            const unsigned u2 = *(const unsigned*)(hb + (long)(p2.x & 0xFFFFF) * OUT_DIM + c);
            const unsigned u3 = *(const unsigned*)(hb + (long)(p3.x & 0xFFFFF) * OUT_DIM + c);
            const float v0 = __int_as_float(p0.y), v1 = __int_as_float(p1.y);
            const float v2 = __int_as_float(p2.y), v3 = __int_as_float(p3.y);
            a0.x += v0 * __uint_as_float(u0 << 16);
            a0.y += v0 * __uint_as_float(u0 & 0xFFFF0000u);
            a1.x += v1 * __uint_as_float(u1 << 16);
            a1.y += v1 * __uint_as_float(u1 & 0xFFFF0000u);
            a2.x += v2 * __uint_as_float(u2 << 16);
            a2.y += v2 * __uint_as_float(u2 & 0xFFFF0000u);
            a3.x += v3 * __uint_as_float(u3 << 16);
            a3.y += v3 * __uint_as_float(u3 & 0xFFFF0000u);
        }
        for (; j < re; ++j) {
            const int2 p0 = lp[j];
            const unsigned u0 = *(const unsigned*)(hb + (long)(p0.x & 0xFFFFF) * OUT_DIM + c);
            const float v0 = __int_as_float(p0.y);
            a0.x += v0 * __uint_as_float(u0 << 16);
            a0.y += v0 * __uint_as_float(u0 & 0xFFFF0000u);
        }
        float2 o;
        o.x = bb.x + (a0.x + a1.x) + (a2.x + a3.x);
        o.y = bb.y + (a0.y + a1.y) + (a2.y + a3.y);
        *(float2*)(out + (long)node * OUT_DIM + c) = o;
    }
}

// ---------------------------------------------------------------------------
extern "C" void kernel_launch(void* const* d_in, const int* in_sizes, int n_in,
                              void* d_out, int out_size, void* d_ws, size_t ws_size,
                              hipStream_t stream) {
    const float* X     = (const float*)d_in[0];
    const int*   esrc  = (const int*)d_in[1];
    const int*   edst  = (const int*)d_in[2];
    const float* evals = (const float*)d_in[3];
    const float* W     = (const float*)d_in[4];
    const float* b     = (const float*)d_in[5];
    float* out = (float*)d_out;

    // workspace layout (bytes)
    char* ws = (char*)d_ws;
    unsigned short* hb = (unsigned short*)(ws);                  // 25,600,000
    int2* pairs        = (int2*)(ws + 25600000);                 // 32,010,240
    int*  cursor       = (int*) (ws + 25600000 + 32010240);      //      6,252
    unsigned short* Wf = (unsigned short*)(ws + 57616496);       //     65,536

    wconv_kernel<<<dim3(16), dim3(256), 0, stream>>>(W, Wf);
    zero_cursor_kernel<<<dim3((NB + 255) / 256), dim3(256), 0, stream>>>(cursor);
    partition_kernel<<<dim3(PBLK), dim3(512), 0, stream>>>(esrc, edst, evals, cursor, pairs);
    gemm_kernel<<<dim3((N_NODES + 63) / 64), dim3(256), 0, stream>>>(X, Wf, hb);
    gather_kernel<<<dim3(NB), dim3(256), 0, stream>>>(cursor, pairs, hb, b, out);
}

// Round 7
// 397.755 us; speedup vs baseline: 6.8164x; 1.0024x over previous
//
#include <hip/hip_runtime.h>

#define N_NODES 100000
#define IN_DIM 256
#define OUT_DIM 128
#define N_EDGES 3200000

#define NB 1563            // ceil(100000 / 64) buckets of 64 dst nodes
#define CAP 2560           // bucket capacity; mean 2048, sigma ~45 -> 11 sigma slack
#define PTILE 6400         // edges per partition block
#define PBLK 500           // 500 * 6400 = 3.2M exactly
#define GBLK 782           // ceil(100000 / 128) gemm blocks (8 waves x 16 rows)

typedef __attribute__((ext_vector_type(8))) short short8;   // 8 bf16 (4 VGPRs)
typedef __attribute__((ext_vector_type(4))) float float4v;  // 4 f32 acc

// round-nearest-even f32 -> bf16 bits
__device__ __forceinline__ unsigned short f2bf(float f) {
    union { float f; unsigned int u; } v; v.f = f;
    unsigned int r = v.u + 0x7FFF + ((v.u >> 16) & 1);
    return (unsigned short)(r >> 16);
}

// ---------------------------------------------------------------------------
// Kernel 0 (setup): blocks 0-15 swizzle W into bf16 MFMA B-fragment-major
// order (fragment f=(q*8+ct)*64+lane holds B[k=q*32+(lane>>4)*8+j][n=ct*16+
// (lane&15)] as 16 contiguous bytes); blocks 16-22 zero the bucket cursors.
// ---------------------------------------------------------------------------
__global__ __launch_bounds__(256) void setup_kernel(const float* __restrict__ W,
                                                    unsigned short* __restrict__ Wf,
                                                    int* __restrict__ cursor) {
    if (blockIdx.x < 16) {
        const int f = blockIdx.x * 256 + threadIdx.x;      // < 4096
        const int lane = f & 63;
        const int qc = f >> 6;
        const int q = qc >> 3, ct = qc & 7;
        const int n = ct * 16 + (lane & 15);
        const int k0 = q * 32 + (lane >> 4) * 8;
        unsigned int o[4];
#pragma unroll
        for (int jj = 0; jj < 4; ++jj) {
            const unsigned short lo = f2bf(W[(k0 + 2 * jj) * OUT_DIM + n]);
            const unsigned short hi = f2bf(W[(k0 + 2 * jj + 1) * OUT_DIM + n]);
            o[jj] = (unsigned)lo | ((unsigned)hi << 16);
        }
        ((uint4*)Wf)[f] = make_uint4(o[0], o[1], o[2], o[3]);
    } else {
        const int i = (blockIdx.x - 16) * 256 + threadIdx.x;
        if (i < NB) cursor[i] = 0;
    }
}

// ---------------------------------------------------------------------------
// Kernel 1 (fused): blocks [0,PBLK) partition edges into 64-node dst-buckets
// (two-pass LDS histogram; pair.x = src | (dst&63)<<20, pair.y = bits(val));
// blocks [PBLK, PBLK+GBLK) compute hb(bf16) = X @ W via mfma_f32_16x16x32_bf16.
// Fusing makes latency-bound partition waves and MFMA-bound gemm waves
// co-resident per CU (separate pipes co-schedule; partition alone had only
// 8 waves/CU in R6). 32 KB LDS union: partition hist/base | gemm store stage.
// ---------------------------------------------------------------------------
__global__ __launch_bounds__(512, 4) void fused_kernel(const float* __restrict__ X,
                                                       const unsigned short* __restrict__ Wf,
                                                       unsigned short* __restrict__ hb,
                                                       const int* __restrict__ src,
                                                       const int* __restrict__ dst,
                                                       const float* __restrict__ vals,
                                                       int* __restrict__ cursor,
                                                       int2* __restrict__ pairs) {
    __shared__ int smem[8192];                         // 32 KB union
    const int tid = threadIdx.x;

    if (blockIdx.x < PBLK) {
        // ================= partition branch =================
        int* lhist = smem;
        int* lbase = smem + NB;
        const int base = blockIdx.x * PTILE;
        const int lim = base + PTILE;

        for (int i = tid; i < NB; i += 512) lhist[i] = 0;
        __syncthreads();

#pragma unroll
        for (int k = 0; k < 13; ++k) {                 // 13*512 >= 6400
            const int e = base + tid + k * 512;
            if (e < lim) atomicAdd(&lhist[dst[e] >> 6], 1);
        }
        __syncthreads();

        for (int i = tid; i < NB; i += 512) {
            const int c = lhist[i];
            if (c) lbase[i] = atomicAdd(&cursor[i], c);
        }
        __syncthreads();
        for (int i = tid; i < NB; i += 512) lhist[i] = 0;
        __syncthreads();

#pragma unroll
        for (int k = 0; k < 13; ++k) {
            const int e = base + tid + k * 512;
            if (e < lim) {
                const int d = dst[e];                  // L1/L2-hot re-read
                const int b = d >> 6;
                const int r = atomicAdd(&lhist[b], 1);
                const int pos = lbase[b] + r;
                if (pos < CAP)                          // 11-sigma overflow guard
                    pairs[(long)b * CAP + pos] =
                        make_int2(src[e] | ((d & 63) << 20), __float_as_int(vals[e]));
            }
        }
    } else {
        // ================= gemm branch =================
        const int bid = blockIdx.x - PBLK;             // 0..GBLK-1
        const int wid = tid >> 6;                      // 8 waves x 16 rows
        const int lane = tid & 63;
        const int m = lane & 15;
        const int quad = lane >> 4;
        const int row0 = bid * 128 + wid * 16;

        // load all 8 A fragments (A[m=lane&15][k=quad*8+j], verified layout)
        const int rl = min(row0 + m, N_NODES - 1);     // clamp tail reads
        const float* xr = X + (long)rl * IN_DIM + quad * 8;
        short8 afrag[8];
#pragma unroll
        for (int q = 0; q < 8; ++q) {
            const float4 xa = *(const float4*)(xr + q * 32);
            const float4 xb = *(const float4*)(xr + q * 32 + 4);
            short8 f;
            f[0] = (short)f2bf(xa.x); f[1] = (short)f2bf(xa.y);
            f[2] = (short)f2bf(xa.z); f[3] = (short)f2bf(xa.w);
            f[4] = (short)f2bf(xb.x); f[5] = (short)f2bf(xb.y);
            f[6] = (short)f2bf(xb.z); f[7] = (short)f2bf(xb.w);
            afrag[q] = f;
        }

        // per-wave private 4 KB store stage (in-order DS: no barrier needed)
        unsigned short* stage = (unsigned short*)smem + wid * 2048;
        const short8* wfrag = (const short8*)Wf;
#pragma unroll 1
        for (int ct = 0; ct < 8; ++ct) {
            float4v acc = {0.f, 0.f, 0.f, 0.f};
#pragma unroll
            for (int q = 0; q < 8; ++q) {
                const short8 bfr = wfrag[(q * 8 + ct) * 64 + lane];
                acc = __builtin_amdgcn_mfma_f32_16x16x32_bf16(afrag[q], bfr, acc, 0, 0, 0);
            }
            // C/D: col=lane&15, row=quad*4+reg (m89-verified)
#pragma unroll
            for (int r = 0; r < 4; ++r)
                stage[(quad * 4 + r) * 128 + ct * 16 + m] = f2bf(acc[r]);
        }

        // coalesced writeback: 4 x (ds_read_b128 + dwordx4), 1 KB contiguous
#pragma unroll
        for (int j = 0; j < 4; ++j) {
            const uint4 vdata = *(const uint4*)(stage + j * 512 + lane * 8);
            const int row_r = row0 + j * 4 + quad;
            if (row_r < N_NODES)
                *(uint4*)(hb + (long)row_r * OUT_DIM + m * 8) = vdata;
        }
    }
}

// ---------------------------------------------------------------------------
// Kernel 2: bucket gather-reduce (counting-sort to LDS + register acc).
// Phase 2 now unrolled x8 for deeper MLP against L2/L3 gather latency.
// ---------------------------------------------------------------------------
__global__ __launch_bounds__(256) void gather_kernel(const int* __restrict__ cursor,
                                                     const int2* __restrict__ pairs,
                                                     const unsigned short* __restrict__ hb,
                                                     const float* __restrict__ bias,
                                                     float* __restrict__ out) {
    __shared__ int2 lp[CAP];                           // 20,480 B sorted pairs
    __shared__ int rcnt[64];
    __shared__ int rbase[64];
    const int blk = blockIdx.x;
    const int tid = threadIdx.x;
    const int wid = tid >> 6;
    const int lane = tid & 63;
    const int c = lane * 2;                            // cols {c, c+1}

    const long beg = (long)blk * CAP;
    const int cnt = min(cursor[blk], CAP);

    if (tid < 64) rcnt[tid] = 0;
    __syncthreads();

    // phase 1a: rank (CAP = 10 * 256 exactly)
    int2 sp[10];
    int  sr[10];
#pragma unroll
    for (int k = 0; k < 10; ++k) {
        const int i = tid + k * 256;
        sr[k] = -1;
        if (i < cnt) {
            const int2 p = pairs[beg + i];
            const int r = (p.x >> 20) & 63;
            const int rk = atomicAdd(&rcnt[r], 1);     // native LDS int atomic
            sp[k] = p;
            sr[k] = (r << 13) | rk;
        }
    }
    __syncthreads();

    // phase 1b: exclusive scan of 64 row counts (wave 0, shfl scan)
    if (wid == 0) {
        const int v = rcnt[lane];
        int incl = v;
#pragma unroll
        for (int off = 1; off < 64; off <<= 1) {
            const int t = __shfl_up(incl, off);
            if (lane >= off) incl += t;
        }
        rbase[lane] = incl - v;
    }
    __syncthreads();

    // phase 1c: scatter into sorted LDS array
#pragma unroll
    for (int k = 0; k < 10; ++k) {
        if (sr[k] >= 0)
            lp[rbase[sr[k] >> 13] + (sr[k] & 0x1FFF)] = sp[k];
    }
    __syncthreads();

    // phase 2: per-row register accumulation, 8-deep MLP
    const float2 bb = *(const float2*)(bias + c);
#pragma unroll 1
    for (int rr = 0; rr < 16; ++rr) {
        const int r = wid * 16 + rr;
        const int node = blk * 64 + r;
        if (node >= N_NODES) break;
        const int rb = rbase[r];
        const int re = rb + rcnt[r];

        float2 acc[8];
#pragma unroll
        for (int t = 0; t < 8; ++t) acc[t] = make_float2(0.f, 0.f);

        int j = rb;
        for (; j + 7 < re; j += 8) {
            int2 p[8];
            unsigned u[8];
#pragma unroll
            for (int t = 0; t < 8; ++t) p[t] = lp[j + t];
#pragma unroll
            for (int t = 0; t < 8; ++t)
                u[t] = *(const unsigned*)(hb + (long)(p[t].x & 0xFFFFF) * OUT_DIM + c);
#pragma unroll
            for (int t = 0; t < 8; ++t) {
                const float v = __int_as_float(p[t].y);
                acc[t].x += v * __uint_as_float(u[t] << 16);
                acc[t].y += v * __uint_as_float(u[t] & 0xFFFF0000u);
            }
        }
        for (; j < re; ++j) {
            const int2 p0 = lp[j];
            const unsigned u0 = *(const unsigned*)(hb + (long)(p0.x & 0xFFFFF) * OUT_DIM + c);
            const float v0 = __int_as_float(p0.y);
            acc[0].x += v0 * __uint_as_float(u0 << 16);
            acc[0].y += v0 * __uint_as_float(u0 & 0xFFFF0000u);
        }
        float2 o;
        o.x = bb.x + ((acc[0].x + acc[1].x) + (acc[2].x + acc[3].x))
                   + ((acc[4].x + acc[5].x) + (acc[6].x + acc[7].x));
        o.y = bb.y + ((acc[0].y + acc[1].y) + (acc[2].y + acc[3].y))
                   + ((acc[4].y + acc[5].y) + (acc[6].y + acc[7].y));
        *(float2*)(out + (long)node * OUT_DIM + c) = o;
    }
}

// ---------------------------------------------------------------------------
extern "C" void kernel_launch(void* const* d_in, const int* in_sizes, int n_in,
                              void* d_out, int out_size, void* d_ws, size_t ws_size,
                              hipStream_t stream) {
    const float* X     = (const float*)d_in[0];
    const int*   esrc  = (const int*)d_in[1];
    const int*   edst  = (const int*)d_in[2];
    const float* evals = (const float*)d_in[3];
    const float* W     = (const float*)d_in[4];
    const float* b     = (const float*)d_in[5];
    float* out = (float*)d_out;

    // workspace layout (bytes)
    char* ws = (char*)d_ws;
    unsigned short* hb = (unsigned short*)(ws);                  // 25,600,000
    int2* pairs        = (int2*)(ws + 25600000);                 // 32,010,240
    int*  cursor       = (int*) (ws + 25600000 + 32010240);      //      6,252
    unsigned short* Wf = (unsigned short*)(ws + 57616496);       //     65,536

    setup_kernel<<<dim3(23), dim3(256), 0, stream>>>(W, Wf, cursor);
    fused_kernel<<<dim3(PBLK + GBLK), dim3(512), 0, stream>>>(X, Wf, hb,
                                                              esrc, edst, evals,
                                                              cursor, pairs);
    gather_kernel<<<dim3(NB), dim3(256), 0, stream>>>(cursor, pairs, hb, b, out);
}